// Round 8
// baseline (66.632 us; speedup 1.0000x reference)
//
#include <hip/hip_runtime.h>
#include <stdint.h>

// QuantDenseModelLarge on gfx950 — MFMA formulation.
// Round 8 = round 6/7 (62 µs) + explicit x-load hoist.
// Theory: the k-tile loop serialized ~4 HBM round-trips per block-round because the
// scheduler wouldn't keep all 48 loads in flight. Hoisting the 16 x-f32x4 loads into
// named registers (64 VGPR) + sched_barrier(0) turns that into ONE ~900cy wait,
// progressively drained (compiler emits vmcnt(14), vmcnt(12), ... per tile).
//
// Exact identities:
//   quant weights = qw * sw, qw int in [-7,7]  -> exact in bf16
//   QuantReLU out = qa * s,  qa int in [0,255] -> exact in bf16
//   layers 2/3/out: D = sum(qa*qw) exact in f32; y = D*(s*sw)
//   layer 1: x == hi + lo1 + lo2 EXACTLY (3 bf16 truncation limbs cover 24 bits)
//
// MFMA layout (hardware-verified via learn_hip m89/m92 ref-checked GEMMs):
//   A (16x32): lane l holds A[m = l&15][k = 8*(l>>4) + j], j=0..7
//   B (32x16): lane l holds B[k = 8*(l>>4) + j][n = l&15]
//   C/D      : lane l, reg r holds D[row = 4*(l>>4) + r][col = l&15]

typedef __attribute__((ext_vector_type(4))) float  f32x4;
typedef __attribute__((ext_vector_type(8))) short  bf16x8;
typedef __attribute__((ext_vector_type(4))) unsigned int u32x4;

namespace {
constexpr int B_  = 131072;
constexpr int IN_ = 256;
constexpr int H_  = 58;
constexpr int C_  = 12;

// ws byte offsets
constexpr int W1F = 0;        // [ht4][kt8][lane64][j8] bf16 = 32768 B
constexpr int W2F = 32768;    // [ht4][kt2][lane64][j8] bf16 =  8192 B
constexpr int W3F = 40960;    //                                8192 B
constexpr int WOF = 49152;    // [kt2][lane64][j8]      bf16 =  2048 B
constexpr int PAR = 51200;    // 3*64 {A,b} f32 | bo[16] | {inv1,inv2,inv3,So}
constexpr int PAR_FLOATS = 404;
constexpr int PITCH = 144;    // bounce-tile row pitch (bytes): 128 data + 16 pad
}

__device__ __forceinline__ uint32_t fu(float f) { return __float_as_uint(f); }
__device__ __forceinline__ float    uf(uint32_t u) { return __uint_as_float(u); }
__device__ __forceinline__ float    truncbf(float v) { return uf(fu(v) & 0xffff0000u); }
// pack bf16(a) into low16, bf16(b) into high16 (truncation; exact for ints/limbs)
__device__ __forceinline__ uint32_t packbf(float a, float b) {
  return (fu(a) >> 16) | (fu(b) & 0xffff0000u);
}

__device__ __forceinline__ f32x4 MFMA(u32x4 a, bf16x8 b, f32x4 c) {
  union { u32x4 u; bf16x8 s; } ua; ua.u = a;
  return __builtin_amdgcn_mfma_f32_16x16x32_bf16(ua.s, b, c, 0, 0, 0);
}

// ---------------- prep: quantize + fragment-major arrange + param tables ----------------
__global__ void prep_kernel(
    const float* __restrict__ W1, const float* __restrict__ W2,
    const float* __restrict__ W3, const float* __restrict__ Wo,
    const float* __restrict__ g1, const float* __restrict__ b1, const float* __restrict__ s1,
    const float* __restrict__ g2, const float* __restrict__ b2, const float* __restrict__ s2,
    const float* __restrict__ g3, const float* __restrict__ b3, const float* __restrict__ s3,
    const float* __restrict__ bo,
    uint8_t* __restrict__ wsb)
{
  __shared__ float red[256];
  const int t = threadIdx.x;
  const int blk = blockIdx.x;
  const float* W; int n;
  switch (blk) {
    case 0: W = W1; n = H_ * IN_; break;
    case 1: W = W2; n = H_ * H_;  break;
    case 2: W = W3; n = H_ * H_;  break;
    default: W = Wo; n = C_ * H_; break;
  }
  float m = 0.f;
  for (int i = t; i < n; i += 256) m = fmaxf(m, fabsf(W[i]));
  red[t] = m;
  __syncthreads();
  for (int s = 128; s > 0; s >>= 1) { if (t < s) red[t] = fmaxf(red[t], red[t + s]); __syncthreads(); }
  const float sw = red[0] / 7.0f;   // per-tensor symmetric, qmax = 7

  float* pp = (float*)(wsb + PAR);

  if (blk == 0) {
    unsigned short* fr = (unsigned short*)(wsb + W1F);
    for (int i = t; i < 16384; i += 256) {
      const int j = i & 7, ln = (i >> 3) & 63, kt = (i >> 9) & 7, ht = (i >> 12) & 3;
      const int h = (ht << 4) | (ln & 15);
      const int k = (kt << 5) | (((ln >> 4) & 3) << 3) | j;
      float q = 0.f;
      if (h < H_) q = fminf(fmaxf(rintf(W1[h * IN_ + k] / sw), -7.f), 7.f);
      fr[i] = (unsigned short)(fu(q) >> 16);   // small ints exact in bf16
    }
    if (t < 64) {
      pp[2 * t]     = (t < H_) ? sw * g1[t] : 0.f;
      pp[2 * t + 1] = (t < H_) ? b1[t] : 0.f;
    }
    if (t == 0) pp[400] = 1.0f / s1[0];
  } else if (blk == 1) {
    unsigned short* fr = (unsigned short*)(wsb + W2F);
    for (int i = t; i < 4096; i += 256) {
      const int j = i & 7, ln = (i >> 3) & 63, kt = (i >> 9) & 1, ht = (i >> 10) & 3;
      const int h = (ht << 4) | (ln & 15);
      const int k = (kt << 5) | (((ln >> 4) & 3) << 3) | j;
      float q = 0.f;
      if (h < H_ && k < H_) q = fminf(fmaxf(rintf(W2[h * H_ + k] / sw), -7.f), 7.f);
      fr[i] = (unsigned short)(fu(q) >> 16);
    }
    if (t < 64) {
      pp[128 + 2 * t]     = (t < H_) ? s1[0] * sw * g2[t] : 0.f;
      pp[128 + 2 * t + 1] = (t < H_) ? b2[t] : 0.f;
    }
    if (t == 0) pp[401] = 1.0f / s2[0];
  } else if (blk == 2) {
    unsigned short* fr = (unsigned short*)(wsb + W3F);
    for (int i = t; i < 4096; i += 256) {
      const int j = i & 7, ln = (i >> 3) & 63, kt = (i >> 9) & 1, ht = (i >> 10) & 3;
      const int h = (ht << 4) | (ln & 15);
      const int k = (kt << 5) | (((ln >> 4) & 3) << 3) | j;
      float q = 0.f;
      if (h < H_ && k < H_) q = fminf(fmaxf(rintf(W3[h * H_ + k] / sw), -7.f), 7.f);
      fr[i] = (unsigned short)(fu(q) >> 16);
    }
    if (t < 64) {
      pp[256 + 2 * t]     = (t < H_) ? s2[0] * sw * g3[t] : 0.f;
      pp[256 + 2 * t + 1] = (t < H_) ? b3[t] : 0.f;
    }
    if (t == 0) pp[402] = 1.0f / s3[0];
  } else {
    unsigned short* fr = (unsigned short*)(wsb + WOF);
    for (int i = t; i < 1024; i += 256) {
      const int j = i & 7, ln = (i >> 3) & 63, kt = (i >> 9) & 1;
      const int h = ln & 15;
      const int k = (kt << 5) | (((ln >> 4) & 3) << 3) | j;
      float q = 0.f;
      if (h < C_ && k < H_) q = fminf(fmaxf(rintf(Wo[h * H_ + k] / sw), -7.f), 7.f);
      fr[i] = (unsigned short)(fu(q) >> 16);
    }
    if (t < 16) pp[384 + t] = (t < C_) ? bo[t] : 0.f;
    if (t == 0) pp[403] = s3[0] * sw;
  }
}

// ---------------- epilogue: BN + QuantReLU -> bf16 ints -> per-wave LDS bounce -> B-frags ----------------
__device__ __forceinline__ void epilog(
    const f32x4 (&acc)[4], const float* __restrict__ pars, int L, float inv,
    uint8_t* bw, int g, int c, bf16x8 (&bfr)[2])
{
  const float* pb = pars + L * 128 + 8 * g;   // {A(h),b(h)} pairs, h = 16ht+4g+r
#pragma unroll
  for (int ht = 0; ht < 4; ++ht) {
    float q[4];
#pragma unroll
    for (int r = 0; r < 4; ++r) {
      const float y = fmaf(acc[ht][r], pb[32 * ht + 2 * r], pb[32 * ht + 2 * r + 1]);
      q[r] = fminf(rintf(fmaxf(y, 0.f) * inv), 255.f);
    }
    uint8_t* bp = bw + c * PITCH + 32 * ht + 8 * g;   // row c, bytes 2h..2h+7
    *(uint32_t*)(bp)     = packbf(q[0], q[1]);
    *(uint32_t*)(bp + 4) = packbf(q[2], q[3]);
  }
  // same-wave cross-lane exchange: DS ops from one wave are processed in order
#pragma unroll
  for (int kt = 0; kt < 2; ++kt) {
    const uint8_t* rp = bw + c * PITCH + 64 * kt + 16 * g;  // k = 32kt+8g+j
    union { u32x4 u; bf16x8 s; } uv;
    uv.u = *(const u32x4*)rp;
    bfr[kt] = uv.s;
  }
}

__global__ __launch_bounds__(256, 2) void fused_mfma_kernel(
    const float* __restrict__ x, const uint8_t* __restrict__ wsb,
    float* __restrict__ out)
{
  __shared__ __align__(16) uint8_t bnc[4][16 * PITCH];  // per-wave bounce tiles
  __shared__ __align__(16) float pars[PAR_FLOATS];

  const int t = threadIdx.x;
  const int w = t >> 6, l = t & 63, g = (l >> 4) & 3, c = l & 15;
  const size_t rowbase = (size_t)blockIdx.x * 64;

  // strided load — 404 floats, 256 threads
  for (int i = t; i < PAR_FLOATS; i += 256) pars[i] = ((const float*)(wsb + PAR))[i];
  __syncthreads();   // only block-wide barrier

  const float inv1 = pars[400], inv2 = pars[401], inv3 = pars[402], So = pars[403];

  // this lane's batch row (B-fragment n = l&15); k-slice owned: 8g..8g+7 (+32s)
  const float* __restrict__ xrow = x + (rowbase + 16 * w + c) * IN_;

  // ---- Phase 1: hoist ALL x loads (16 x f32x4 = 64 VGPR) before any MFMA ----
  f32x4 xr[16];
#pragma unroll
  for (int s = 0; s < 8; ++s) {
    xr[2 * s]     = *(const f32x4*)(xrow + 32 * s + 8 * g);
    xr[2 * s + 1] = *(const f32x4*)(xrow + 32 * s + 8 * g + 4);
  }
  // Pin the loads above the compute loop; compiler still drains vmcnt progressively.
  __builtin_amdgcn_sched_barrier(0);

  f32x4 acc[4];
#pragma unroll
  for (int ht = 0; ht < 4; ++ht) acc[ht] = f32x4{0.f, 0.f, 0.f, 0.f};

  // ---- Layer 1: 8 k-tiles of 32, 3 exact bf16 limbs ----
#pragma unroll
  for (int s = 0; s < 8; ++s) {
    u32x4 wf[4];
#pragma unroll
    for (int ht = 0; ht < 4; ++ht)
      wf[ht] = *(const u32x4*)(wsb + W1F + (size_t)(((ht * 8 + s) * 64) + l) * 16);

    const f32x4 e0 = xr[2 * s];
    const f32x4 e1 = xr[2 * s + 1];
    const float el[8] = {e0.x, e0.y, e0.z, e0.w, e1.x, e1.y, e1.z, e1.w};

    float d[8], e2[8];
#pragma unroll
    for (int q = 0; q < 8; ++q) d[q] = el[q] - truncbf(el[q]);   // exact
#pragma unroll
    for (int q = 0; q < 8; ++q) e2[q] = d[q] - truncbf(d[q]);    // exact

    union { uint32_t u[4]; bf16x8 v; } bh, bl1, bl2;
#pragma unroll
    for (int q = 0; q < 4; ++q) {
      bh.u[q]  = packbf(el[2 * q], el[2 * q + 1]);
      bl1.u[q] = packbf(d[2 * q],  d[2 * q + 1]);
      bl2.u[q] = packbf(e2[2 * q], e2[2 * q + 1]);
    }
#pragma unroll
    for (int ht = 0; ht < 4; ++ht) acc[ht] = MFMA(wf[ht], bh.v,  acc[ht]);
#pragma unroll
    for (int ht = 0; ht < 4; ++ht) acc[ht] = MFMA(wf[ht], bl1.v, acc[ht]);
#pragma unroll
    for (int ht = 0; ht < 4; ++ht) acc[ht] = MFMA(wf[ht], bl2.v, acc[ht]);
  }

  uint8_t* bw = &bnc[w][0];
  bf16x8 bfr[2];

  // ---- Layer 2 ----
  epilog(acc, pars, 0, inv1, bw, g, c, bfr);
  f32x4 a2[4];
#pragma unroll
  for (int ht = 0; ht < 4; ++ht) a2[ht] = f32x4{0.f, 0.f, 0.f, 0.f};
#pragma unroll
  for (int kt = 0; kt < 2; ++kt) {
#pragma unroll
    for (int ht = 0; ht < 4; ++ht) {
      const u32x4 wf = *(const u32x4*)(wsb + W2F + (size_t)(((ht * 2 + kt) * 64) + l) * 16);
      a2[ht] = MFMA(wf, bfr[kt], a2[ht]);
    }
  }

  // ---- Layer 3 ----
  epilog(a2, pars, 1, inv2, bw, g, c, bfr);
  f32x4 a3[4];
#pragma unroll
  for (int ht = 0; ht < 4; ++ht) a3[ht] = f32x4{0.f, 0.f, 0.f, 0.f};
#pragma unroll
  for (int kt = 0; kt < 2; ++kt) {
#pragma unroll
    for (int ht = 0; ht < 4; ++ht) {
      const u32x4 wf = *(const u32x4*)(wsb + W3F + (size_t)(((ht * 2 + kt) * 64) + l) * 16);
      a3[ht] = MFMA(wf, bfr[kt], a3[ht]);
    }
  }

  // ---- Output layer ----
  epilog(a3, pars, 2, inv3, bw, g, c, bfr);
  f32x4 ao = f32x4{0.f, 0.f, 0.f, 0.f};
#pragma unroll
  for (int kt = 0; kt < 2; ++kt) {
    const u32x4 wf = *(const u32x4*)(wsb + WOF + (size_t)((kt * 64) + l) * 16);
    ao = MFMA(wf, bfr[kt], ao);
  }

  const float bo0 = pars[384 + 4 * g + 0];
  const float bo1 = pars[384 + 4 * g + 1];
  const float bo2 = pars[384 + 4 * g + 2];
  const float bo3 = pars[384 + 4 * g + 3];
  f32x4 o;
  o.x = fmaf(ao.x, So, bo0);
  o.y = fmaf(ao.y, So, bo1);
  o.z = fmaf(ao.z, So, bo2);
  o.w = fmaf(ao.w, So, bo3);
  if (g < 3)  // out channels 4g..4g+3; only 0..11 exist
    *(f32x4*)(out + (rowbase + 16 * w + c) * C_ + 4 * g) = o;
}

extern "C" void kernel_launch(void* const* d_in, const int* in_sizes, int n_in,
                              void* d_out, int out_size, void* d_ws, size_t ws_size,
                              hipStream_t stream) {
  // 0:x 1:W1 2:g1 3:b1 4:s1 5:W2 6:g2 7:b2 8:s2 9:W3 10:g3 11:b3 12:s3 13:Wo 14:bo
  const float* x  = (const float*)d_in[0];
  const float* W1 = (const float*)d_in[1];
  const float* g1 = (const float*)d_in[2];
  const float* b1 = (const float*)d_in[3];
  const float* s1 = (const float*)d_in[4];
  const float* W2 = (const float*)d_in[5];
  const float* g2 = (const float*)d_in[6];
  const float* b2 = (const float*)d_in[7];
  const float* s2 = (const float*)d_in[8];
  const float* W3 = (const float*)d_in[9];
  const float* g3 = (const float*)d_in[10];
  const float* b3 = (const float*)d_in[11];
  const float* s3 = (const float*)d_in[12];
  const float* Wo = (const float*)d_in[13];
  const float* bo = (const float*)d_in[14];

  uint8_t* ws = (uint8_t*)d_ws;
  float* out = (float*)d_out;

  prep_kernel<<<4, 256, 0, stream>>>(W1, W2, W3, Wo, g1, b1, s1, g2, b2, s2,
                                     g3, b3, s3, bo, ws);
  fused_mfma_kernel<<<B_ / 64, 256, 0, stream>>>(x, ws, out);
}

// Round 9
// 60.665 us; speedup vs baseline: 1.0984x; 1.0984x over previous
//
#include <hip/hip_runtime.h>
#include <stdint.h>

// QuantDenseModelLarge on gfx950 — MFMA formulation.
// Round 9 = round 6 (62 µs, passing) + LDS-staged x via global_load_lds.
// Theory: round 6/7/8 plateau at 62 µs = HBM request-inefficiency (16B/lane
// gathers at 1KB row stride). Stage x with global_load_lds: each DMA covers
// 4 rows x 256B contiguous (full cachelines), double-buffered per-wave 4KB
// chunks, barrier-free, vmcnt(4) per chunk. XOR swizzle (slot ^= row) applied
// to the GLOBAL SOURCE address (LDS dest stays linear, rule #21) and to the
// ds_read offset. Reverts round-8 hoist/sched_barrier.
//
// Exact identities:
//   quant weights = qw * sw, qw int in [-7,7]  -> exact in bf16
//   QuantReLU out = qa * s,  qa int in [0,255] -> exact in bf16
//   layers 2/3/out: D = sum(qa*qw) exact in f32; y = D*(s*sw)
//   layer 1: x == hi + lo1 + lo2 EXACTLY (3 bf16 truncation limbs cover 24 bits)
//
// MFMA layout (hardware-verified via learn_hip m89/m92 ref-checked GEMMs):
//   A (16x32): lane l holds A[m = l&15][k = 8*(l>>4) + j], j=0..7
//   B (32x16): lane l holds B[k = 8*(l>>4) + j][n = l&15]
//   C/D      : lane l, reg r holds D[row = 4*(l>>4) + r][col = l&15]

typedef __attribute__((ext_vector_type(4))) float  f32x4;
typedef __attribute__((ext_vector_type(8))) short  bf16x8;
typedef __attribute__((ext_vector_type(4))) unsigned int u32x4;

namespace {
constexpr int B_  = 131072;
constexpr int IN_ = 256;
constexpr int H_  = 58;
constexpr int C_  = 12;

// ws byte offsets
constexpr int W1F = 0;        // [ht4][kt8][lane64][j8] bf16 = 32768 B
constexpr int W2F = 32768;    // [ht4][kt2][lane64][j8] bf16 =  8192 B
constexpr int W3F = 40960;    //                                8192 B
constexpr int WOF = 49152;    // [kt2][lane64][j8]      bf16 =  2048 B
constexpr int PAR = 51200;    // 3*64 {A,b} f32 | bo[16] | {inv1,inv2,inv3,So}
constexpr int PAR_FLOATS = 404;
constexpr int PITCH = 144;    // bounce-tile row pitch (bytes): 128 data + 16 pad
}

__device__ __forceinline__ uint32_t fu(float f) { return __float_as_uint(f); }
__device__ __forceinline__ float    uf(uint32_t u) { return __uint_as_float(u); }
__device__ __forceinline__ float    truncbf(float v) { return uf(fu(v) & 0xffff0000u); }
// pack bf16(a) into low16, bf16(b) into high16 (truncation; exact for ints/limbs)
__device__ __forceinline__ uint32_t packbf(float a, float b) {
  return (fu(a) >> 16) | (fu(b) & 0xffff0000u);
}

__device__ __forceinline__ f32x4 MFMA(u32x4 a, bf16x8 b, f32x4 c) {
  union { u32x4 u; bf16x8 s; } ua; ua.u = a;
  return __builtin_amdgcn_mfma_f32_16x16x32_bf16(ua.s, b, c, 0, 0, 0);
}

// ---------------- prep: quantize + fragment-major arrange + param tables ----------------
__global__ void prep_kernel(
    const float* __restrict__ W1, const float* __restrict__ W2,
    const float* __restrict__ W3, const float* __restrict__ Wo,
    const float* __restrict__ g1, const float* __restrict__ b1, const float* __restrict__ s1,
    const float* __restrict__ g2, const float* __restrict__ b2, const float* __restrict__ s2,
    const float* __restrict__ g3, const float* __restrict__ b3, const float* __restrict__ s3,
    const float* __restrict__ bo,
    uint8_t* __restrict__ wsb)
{
  __shared__ float red[256];
  const int t = threadIdx.x;
  const int blk = blockIdx.x;
  const float* W; int n;
  switch (blk) {
    case 0: W = W1; n = H_ * IN_; break;
    case 1: W = W2; n = H_ * H_;  break;
    case 2: W = W3; n = H_ * H_;  break;
    default: W = Wo; n = C_ * H_; break;
  }
  float m = 0.f;
  for (int i = t; i < n; i += 256) m = fmaxf(m, fabsf(W[i]));
  red[t] = m;
  __syncthreads();
  for (int s = 128; s > 0; s >>= 1) { if (t < s) red[t] = fmaxf(red[t], red[t + s]); __syncthreads(); }
  const float sw = red[0] / 7.0f;   // per-tensor symmetric, qmax = 7

  float* pp = (float*)(wsb + PAR);

  if (blk == 0) {
    unsigned short* fr = (unsigned short*)(wsb + W1F);
    for (int i = t; i < 16384; i += 256) {
      const int j = i & 7, ln = (i >> 3) & 63, kt = (i >> 9) & 7, ht = (i >> 12) & 3;
      const int h = (ht << 4) | (ln & 15);
      const int k = (kt << 5) | (((ln >> 4) & 3) << 3) | j;
      float q = 0.f;
      if (h < H_) q = fminf(fmaxf(rintf(W1[h * IN_ + k] / sw), -7.f), 7.f);
      fr[i] = (unsigned short)(fu(q) >> 16);   // small ints exact in bf16
    }
    if (t < 64) {
      pp[2 * t]     = (t < H_) ? sw * g1[t] : 0.f;
      pp[2 * t + 1] = (t < H_) ? b1[t] : 0.f;
    }
    if (t == 0) pp[400] = 1.0f / s1[0];
  } else if (blk == 1) {
    unsigned short* fr = (unsigned short*)(wsb + W2F);
    for (int i = t; i < 4096; i += 256) {
      const int j = i & 7, ln = (i >> 3) & 63, kt = (i >> 9) & 1, ht = (i >> 10) & 3;
      const int h = (ht << 4) | (ln & 15);
      const int k = (kt << 5) | (((ln >> 4) & 3) << 3) | j;
      float q = 0.f;
      if (h < H_ && k < H_) q = fminf(fmaxf(rintf(W2[h * H_ + k] / sw), -7.f), 7.f);
      fr[i] = (unsigned short)(fu(q) >> 16);
    }
    if (t < 64) {
      pp[128 + 2 * t]     = (t < H_) ? s1[0] * sw * g2[t] : 0.f;
      pp[128 + 2 * t + 1] = (t < H_) ? b2[t] : 0.f;
    }
    if (t == 0) pp[401] = 1.0f / s2[0];
  } else if (blk == 2) {
    unsigned short* fr = (unsigned short*)(wsb + W3F);
    for (int i = t; i < 4096; i += 256) {
      const int j = i & 7, ln = (i >> 3) & 63, kt = (i >> 9) & 1, ht = (i >> 10) & 3;
      const int h = (ht << 4) | (ln & 15);
      const int k = (kt << 5) | (((ln >> 4) & 3) << 3) | j;
      float q = 0.f;
      if (h < H_ && k < H_) q = fminf(fmaxf(rintf(W3[h * H_ + k] / sw), -7.f), 7.f);
      fr[i] = (unsigned short)(fu(q) >> 16);
    }
    if (t < 64) {
      pp[256 + 2 * t]     = (t < H_) ? s2[0] * sw * g3[t] : 0.f;
      pp[256 + 2 * t + 1] = (t < H_) ? b3[t] : 0.f;
    }
    if (t == 0) pp[402] = 1.0f / s3[0];
  } else {
    unsigned short* fr = (unsigned short*)(wsb + WOF);
    for (int i = t; i < 1024; i += 256) {
      const int j = i & 7, ln = (i >> 3) & 63, kt = (i >> 9) & 1;
      const int h = ln & 15;
      const int k = (kt << 5) | (((ln >> 4) & 3) << 3) | j;
      float q = 0.f;
      if (h < C_ && k < H_) q = fminf(fmaxf(rintf(Wo[h * H_ + k] / sw), -7.f), 7.f);
      fr[i] = (unsigned short)(fu(q) >> 16);
    }
    if (t < 16) pp[384 + t] = (t < C_) ? bo[t] : 0.f;
    if (t == 0) pp[403] = s3[0] * sw;
  }
}

// ---------------- epilogue: BN + QuantReLU -> bf16 ints -> per-wave LDS bounce -> B-frags ----------------
__device__ __forceinline__ void epilog(
    const f32x4 (&acc)[4], const float* __restrict__ pars, int L, float inv,
    uint8_t* bw, int g, int c, bf16x8 (&bfr)[2])
{
  const float* pb = pars + L * 128 + 8 * g;   // {A(h),b(h)} pairs, h = 16ht+4g+r
#pragma unroll
  for (int ht = 0; ht < 4; ++ht) {
    float q[4];
#pragma unroll
    for (int r = 0; r < 4; ++r) {
      const float y = fmaf(acc[ht][r], pb[32 * ht + 2 * r], pb[32 * ht + 2 * r + 1]);
      q[r] = fminf(rintf(fmaxf(y, 0.f) * inv), 255.f);
    }
    uint8_t* bp = bw + c * PITCH + 32 * ht + 8 * g;   // row c, bytes 2h..2h+7
    *(uint32_t*)(bp)     = packbf(q[0], q[1]);
    *(uint32_t*)(bp + 4) = packbf(q[2], q[3]);
  }
  // same-wave cross-lane exchange: DS ops from one wave are processed in order
#pragma unroll
  for (int kt = 0; kt < 2; ++kt) {
    const uint8_t* rp = bw + c * PITCH + 64 * kt + 16 * g;  // k = 32kt+8g+j
    union { u32x4 u; bf16x8 s; } uv;
    uv.u = *(const u32x4*)rp;
    bfr[kt] = uv.s;
  }
}

__global__ __launch_bounds__(256, 2) void fused_mfma_kernel(
    const float* __restrict__ x, const uint8_t* __restrict__ wsb,
    float* __restrict__ out)
{
  // x staging: 2 buffers x (4 waves x 16 rows x 64 floats) = 32 KB.
  // Per-wave slice: 16 rows x 256B. LDS row r holds global 16B-slot (s ^ r)
  // at slot s (XOR pre-applied to the global source address; dest is linear).
  __shared__ __align__(16) float xs[2][4096];
  __shared__ __align__(16) uint8_t bnc[4][16 * PITCH];  // per-wave bounce tiles
  __shared__ __align__(16) float pars[PAR_FLOATS];

  const int t = threadIdx.x;
  const int w = t >> 6, l = t & 63, g = (l >> 4) & 3, c = l & 15;
  const size_t rowbase = (size_t)blockIdx.x * 64;

  // strided load — 404 floats, 256 threads
  for (int i = t; i < PAR_FLOATS; i += 256) pars[i] = ((const float*)(wsb + PAR))[i];
  __syncthreads();   // only block-wide barrier

  const float inv1 = pars[400], inv2 = pars[401], inv3 = pars[402], So = pars[403];

  // Stage one 64-float chunk of this wave's 16 rows into its own LDS slice.
  // DMA i covers LDS rows 4i..4i+3 linearly (lane l -> row 4i+(l>>4), slot l&15);
  // the global source slot is (l&15) ^ row — the read side undoes the XOR.
#define STAGE(ch_, buf_)                                                             \
  {                                                                                  \
    _Pragma("unroll")                                                                \
    for (int i = 0; i < 4; ++i) {                                                    \
      const int row16 = 4 * i + g;            /* this lane's dest row (= l>>4) */    \
      const int slot_src = (l & 15) ^ row16;                                         \
      const float* src = x + (rowbase + 16 * w + row16) * IN_                        \
                           + (ch_) * 64 + 4 * slot_src;                              \
      void* dst = (char*)&xs[buf_][0] + w * 4096 + i * 1024;                         \
      __builtin_amdgcn_global_load_lds(                                              \
          (const __attribute__((address_space(1))) void*)src,                        \
          (__attribute__((address_space(3))) void*)dst, 16, 0, 0);                   \
    }                                                                                \
  }

  f32x4 acc[4];
#pragma unroll
  for (int ht = 0; ht < 4; ++ht) acc[ht] = f32x4{0.f, 0.f, 0.f, 0.f};

  STAGE(0, 0);

  // ---- Layer 1: 4 chunks x 2 k-tiles, 3 exact bf16 limbs, barrier-free dbuf ----
#pragma unroll
  for (int ch = 0; ch < 4; ++ch) {
    if (ch < 3) STAGE(ch + 1, (ch + 1) & 1);
    // Wait for this chunk's 4 stages; the 4 newest outstanding are next chunk's.
    asm volatile("s_waitcnt vmcnt(4)" ::: "memory");

    const char* xb = (const char*)&xs[ch & 1][0] + w * 4096 + c * 256;  // row c slice
#pragma unroll
    for (int s2 = 0; s2 < 2; ++s2) {
      const int s = 2 * ch + s2;   // global k-tile index 0..7
      u32x4 wf[4];
#pragma unroll
      for (int ht = 0; ht < 4; ++ht)
        wf[ht] = *(const u32x4*)(wsb + W1F + (size_t)(((ht * 8 + s) * 64) + l) * 16);

      // wanted global slots 8*s2+2g, 8*s2+2g+1 of row c  ->  LDS slot ^= c
      const int w0 = (128 * s2 + 32 * g)      ^ (c << 4);
      const int w1 = (128 * s2 + 32 * g + 16) ^ (c << 4);
      const f32x4 e0 = *(const f32x4*)(xb + w0);
      const f32x4 e1 = *(const f32x4*)(xb + w1);
      const float el[8] = {e0.x, e0.y, e0.z, e0.w, e1.x, e1.y, e1.z, e1.w};

      float d[8], e2[8];
#pragma unroll
      for (int q = 0; q < 8; ++q) d[q] = el[q] - truncbf(el[q]);   // exact
#pragma unroll
      for (int q = 0; q < 8; ++q) e2[q] = d[q] - truncbf(d[q]);    // exact

      union { uint32_t u[4]; bf16x8 v; } bh, bl1, bl2;
#pragma unroll
      for (int q = 0; q < 4; ++q) {
        bh.u[q]  = packbf(el[2 * q], el[2 * q + 1]);
        bl1.u[q] = packbf(d[2 * q],  d[2 * q + 1]);
        bl2.u[q] = packbf(e2[2 * q], e2[2 * q + 1]);
      }
#pragma unroll
      for (int ht = 0; ht < 4; ++ht) acc[ht] = MFMA(wf[ht], bh.v,  acc[ht]);
#pragma unroll
      for (int ht = 0; ht < 4; ++ht) acc[ht] = MFMA(wf[ht], bl1.v, acc[ht]);
#pragma unroll
      for (int ht = 0; ht < 4; ++ht) acc[ht] = MFMA(wf[ht], bl2.v, acc[ht]);
    }
  }
#undef STAGE

  uint8_t* bw = &bnc[w][0];
  bf16x8 bfr[2];

  // ---- Layer 2 ----
  epilog(acc, pars, 0, inv1, bw, g, c, bfr);
  f32x4 a2[4];
#pragma unroll
  for (int ht = 0; ht < 4; ++ht) a2[ht] = f32x4{0.f, 0.f, 0.f, 0.f};
#pragma unroll
  for (int kt = 0; kt < 2; ++kt) {
#pragma unroll
    for (int ht = 0; ht < 4; ++ht) {
      const u32x4 wf = *(const u32x4*)(wsb + W2F + (size_t)(((ht * 2 + kt) * 64) + l) * 16);
      a2[ht] = MFMA(wf, bfr[kt], a2[ht]);
    }
  }

  // ---- Layer 3 ----
  epilog(a2, pars, 1, inv2, bw, g, c, bfr);
  f32x4 a3[4];
#pragma unroll
  for (int ht = 0; ht < 4; ++ht) a3[ht] = f32x4{0.f, 0.f, 0.f, 0.f};
#pragma unroll
  for (int kt = 0; kt < 2; ++kt) {
#pragma unroll
    for (int ht = 0; ht < 4; ++ht) {
      const u32x4 wf = *(const u32x4*)(wsb + W3F + (size_t)(((ht * 2 + kt) * 64) + l) * 16);
      a3[ht] = MFMA(wf, bfr[kt], a3[ht]);
    }
  }

  // ---- Output layer ----
  epilog(a3, pars, 2, inv3, bw, g, c, bfr);
  f32x4 ao = f32x4{0.f, 0.f, 0.f, 0.f};
#pragma unroll
  for (int kt = 0; kt < 2; ++kt) {
    const u32x4 wf = *(const u32x4*)(wsb + WOF + (size_t)((kt * 64) + l) * 16);
    ao = MFMA(wf, bfr[kt], ao);
  }

  const float bo0 = pars[384 + 4 * g + 0];
  const float bo1 = pars[384 + 4 * g + 1];
  const float bo2 = pars[384 + 4 * g + 2];
  const float bo3 = pars[384 + 4 * g + 3];
  f32x4 o;
  o.x = fmaf(ao.x, So, bo0);
  o.y = fmaf(ao.y, So, bo1);
  o.z = fmaf(ao.z, So, bo2);
  o.w = fmaf(ao.w, So, bo3);
  if (g < 3)  // out channels 4g..4g+3; only 0..11 exist
    *(f32x4*)(out + (rowbase + 16 * w + c) * C_ + 4 * g) = o;
}

extern "C" void kernel_launch(void* const* d_in, const int* in_sizes, int n_in,
                              void* d_out, int out_size, void* d_ws, size_t ws_size,
                              hipStream_t stream) {
  // 0:x 1:W1 2:g1 3:b1 4:s1 5:W2 6:g2 7:b2 8:s2 9:W3 10:g3 11:b3 12:s3 13:Wo 14:bo
  const float* x  = (const float*)d_in[0];
  const float* W1 = (const float*)d_in[1];
  const float* g1 = (const float*)d_in[2];
  const float* b1 = (const float*)d_in[3];
  const float* s1 = (const float*)d_in[4];
  const float* W2 = (const float*)d_in[5];
  const float* g2 = (const float*)d_in[6];
  const float* b2 = (const float*)d_in[7];
  const float* s2 = (const float*)d_in[8];
  const float* W3 = (const float*)d_in[9];
  const float* g3 = (const float*)d_in[10];
  const float* b3 = (const float*)d_in[11];
  const float* s3 = (const float*)d_in[12];
  const float* Wo = (const float*)d_in[13];
  const float* bo = (const float*)d_in[14];

  uint8_t* ws = (uint8_t*)d_ws;
  float* out = (float*)d_out;

  prep_kernel<<<4, 256, 0, stream>>>(W1, W2, W3, Wo, g1, b1, s1, g2, b2, s2,
                                     g3, b3, s3, bo, ws);
  fused_mfma_kernel<<<B_ / 64, 256, 0, stream>>>(x, ws, out);
}

// Round 10
// 45.728 us; speedup vs baseline: 1.4571x; 1.3267x over previous
//
#include <hip/hip_runtime.h>
#include <stdint.h>

// QuantDenseModelLarge on gfx950 — MFMA formulation.
// Round 10 = round 9 core, but weights/params staged in LDS (the real fix) and
// x reverted to direct global loads (round 6 path; proven equivalent to staging).
//
// Theory: rounds 6-9 all ~61 µs regardless of x-path => shared bottleneck =
// per-wave weight-fragment replication: every wave re-read all 50KB of fragment
// arrays from global (8192 waves -> ~410 MB through L2/L1). Fix: stage the
// 51.6KB ws image into LDS once per block (13 x 4KB global_load_lds chunks,
// linear, 1 barrier); fragment reads become conflict-free ds_read_b128
// (consecutive lanes x 16B) on the LDS port. Global weight traffic 410->102 MB.
// Prep kernel parallelized (4 x 1024 threads) to shrink the serial prefix.
//
// Exact identities:
//   quant weights = qw * sw, qw int in [-7,7]  -> exact in bf16
//   QuantReLU out = qa * s,  qa int in [0,255] -> exact in bf16
//   layers 2/3/out: D = sum(qa*qw) exact in f32; y = D*(s*sw)
//   layer 1: x == hi + lo1 + lo2 EXACTLY (3 bf16 truncation limbs cover 24 bits)
//
// MFMA layout (hardware-verified via learn_hip m89/m92 ref-checked GEMMs):
//   A (16x32): lane l holds A[m = l&15][k = 8*(l>>4) + j], j=0..7
//   B (32x16): lane l holds B[k = 8*(l>>4) + j][n = l&15]
//   C/D      : lane l, reg r holds D[row = 4*(l>>4) + r][col = l&15]

typedef __attribute__((ext_vector_type(4))) float  f32x4;
typedef __attribute__((ext_vector_type(8))) short  bf16x8;
typedef __attribute__((ext_vector_type(4))) unsigned int u32x4;

namespace {
constexpr int B_  = 131072;
constexpr int IN_ = 256;
constexpr int H_  = 58;
constexpr int C_  = 12;

// ws byte offsets (also the LDS image offsets after staging)
constexpr int W1F = 0;        // [ht4][kt8][lane64][j8] bf16 = 32768 B
constexpr int W2F = 32768;    // [ht4][kt2][lane64][j8] bf16 =  8192 B
constexpr int W3F = 40960;    //                                8192 B
constexpr int WOF = 49152;    // [kt2][lane64][j8]      bf16 =  2048 B
constexpr int PAR = 51200;    // 3*64 {A,b} f32 | bo[16] | {inv1,inv2,inv3,So}
constexpr int WS_STAGE = 52816;  // PAR + 404*4, multiple of 16
constexpr int PITCH = 144;    // bounce-tile row pitch (bytes): 128 data + 16 pad
}

__device__ __forceinline__ uint32_t fu(float f) { return __float_as_uint(f); }
__device__ __forceinline__ float    uf(uint32_t u) { return __uint_as_float(u); }
__device__ __forceinline__ float    truncbf(float v) { return uf(fu(v) & 0xffff0000u); }
// pack bf16(a) into low16, bf16(b) into high16 (truncation; exact for ints/limbs)
__device__ __forceinline__ uint32_t packbf(float a, float b) {
  return (fu(a) >> 16) | (fu(b) & 0xffff0000u);
}

__device__ __forceinline__ f32x4 MFMA(u32x4 a, bf16x8 b, f32x4 c) {
  union { u32x4 u; bf16x8 s; } ua; ua.u = a;
  return __builtin_amdgcn_mfma_f32_16x16x32_bf16(ua.s, b, c, 0, 0, 0);
}

// ---------------- prep: quantize + fragment-major arrange + param tables ----------------
__global__ void prep_kernel(
    const float* __restrict__ W1, const float* __restrict__ W2,
    const float* __restrict__ W3, const float* __restrict__ Wo,
    const float* __restrict__ g1, const float* __restrict__ b1, const float* __restrict__ s1,
    const float* __restrict__ g2, const float* __restrict__ b2, const float* __restrict__ s2,
    const float* __restrict__ g3, const float* __restrict__ b3, const float* __restrict__ s3,
    const float* __restrict__ bo,
    uint8_t* __restrict__ wsb)
{
  __shared__ float red[1024];
  const int t = threadIdx.x;
  const int blk = blockIdx.x;
  const float* W; int n;
  switch (blk) {
    case 0: W = W1; n = H_ * IN_; break;
    case 1: W = W2; n = H_ * H_;  break;
    case 2: W = W3; n = H_ * H_;  break;
    default: W = Wo; n = C_ * H_; break;
  }
  float m = 0.f;
  for (int i = t; i < n; i += 1024) m = fmaxf(m, fabsf(W[i]));
  red[t] = m;
  __syncthreads();
  for (int s = 512; s > 0; s >>= 1) { if (t < s) red[t] = fmaxf(red[t], red[t + s]); __syncthreads(); }
  const float sw = red[0] / 7.0f;   // per-tensor symmetric, qmax = 7

  float* pp = (float*)(wsb + PAR);

  if (blk == 0) {
    unsigned short* fr = (unsigned short*)(wsb + W1F);
    for (int i = t; i < 16384; i += 1024) {
      const int j = i & 7, ln = (i >> 3) & 63, kt = (i >> 9) & 7, ht = (i >> 12) & 3;
      const int h = (ht << 4) | (ln & 15);
      const int k = (kt << 5) | (((ln >> 4) & 3) << 3) | j;
      float q = 0.f;
      if (h < H_) q = fminf(fmaxf(rintf(W1[h * IN_ + k] / sw), -7.f), 7.f);
      fr[i] = (unsigned short)(fu(q) >> 16);   // small ints exact in bf16
    }
    if (t < 64) {
      pp[2 * t]     = (t < H_) ? sw * g1[t] : 0.f;
      pp[2 * t + 1] = (t < H_) ? b1[t] : 0.f;
    }
    if (t == 0) pp[400] = 1.0f / s1[0];
  } else if (blk == 1) {
    unsigned short* fr = (unsigned short*)(wsb + W2F);
    for (int i = t; i < 4096; i += 1024) {
      const int j = i & 7, ln = (i >> 3) & 63, kt = (i >> 9) & 1, ht = (i >> 10) & 3;
      const int h = (ht << 4) | (ln & 15);
      const int k = (kt << 5) | (((ln >> 4) & 3) << 3) | j;
      float q = 0.f;
      if (h < H_ && k < H_) q = fminf(fmaxf(rintf(W2[h * H_ + k] / sw), -7.f), 7.f);
      fr[i] = (unsigned short)(fu(q) >> 16);
    }
    if (t < 64) {
      pp[128 + 2 * t]     = (t < H_) ? s1[0] * sw * g2[t] : 0.f;
      pp[128 + 2 * t + 1] = (t < H_) ? b2[t] : 0.f;
    }
    if (t == 0) pp[401] = 1.0f / s2[0];
  } else if (blk == 2) {
    unsigned short* fr = (unsigned short*)(wsb + W3F);
    for (int i = t; i < 4096; i += 1024) {
      const int j = i & 7, ln = (i >> 3) & 63, kt = (i >> 9) & 1, ht = (i >> 10) & 3;
      const int h = (ht << 4) | (ln & 15);
      const int k = (kt << 5) | (((ln >> 4) & 3) << 3) | j;
      float q = 0.f;
      if (h < H_ && k < H_) q = fminf(fmaxf(rintf(W3[h * H_ + k] / sw), -7.f), 7.f);
      fr[i] = (unsigned short)(fu(q) >> 16);
    }
    if (t < 64) {
      pp[256 + 2 * t]     = (t < H_) ? s2[0] * sw * g3[t] : 0.f;
      pp[256 + 2 * t + 1] = (t < H_) ? b3[t] : 0.f;
    }
    if (t == 0) pp[402] = 1.0f / s3[0];
  } else {
    unsigned short* fr = (unsigned short*)(wsb + WOF);
    for (int i = t; i < 1024; i += 1024) {
      const int j = i & 7, ln = (i >> 3) & 63, kt = (i >> 9) & 1;
      const int h = ln & 15;
      const int k = (kt << 5) | (((ln >> 4) & 3) << 3) | j;
      float q = 0.f;
      if (h < C_ && k < H_) q = fminf(fmaxf(rintf(Wo[h * H_ + k] / sw), -7.f), 7.f);
      fr[i] = (unsigned short)(fu(q) >> 16);
    }
    if (t < 16) pp[384 + t] = (t < C_) ? bo[t] : 0.f;
    if (t == 0) pp[403] = s3[0] * sw;
  }
}

// ---------------- epilogue: BN + QuantReLU -> bf16 ints -> per-wave LDS bounce -> B-frags ----------------
__device__ __forceinline__ void epilog(
    const f32x4 (&acc)[4], const float* pars, int L, float inv,
    uint8_t* bw, int g, int c, bf16x8 (&bfr)[2])
{
  const float* pb = pars + L * 128 + 8 * g;   // {A(h),b(h)} pairs, h = 16ht+4g+r
#pragma unroll
  for (int ht = 0; ht < 4; ++ht) {
    float q[4];
#pragma unroll
    for (int r = 0; r < 4; ++r) {
      const float y = fmaf(acc[ht][r], pb[32 * ht + 2 * r], pb[32 * ht + 2 * r + 1]);
      q[r] = fminf(rintf(fmaxf(y, 0.f) * inv), 255.f);
    }
    uint8_t* bp = bw + c * PITCH + 32 * ht + 8 * g;   // row c, bytes 2h..2h+7
    *(uint32_t*)(bp)     = packbf(q[0], q[1]);
    *(uint32_t*)(bp + 4) = packbf(q[2], q[3]);
  }
  // same-wave cross-lane exchange: DS ops from one wave are processed in order
#pragma unroll
  for (int kt = 0; kt < 2; ++kt) {
    const uint8_t* rp = bw + c * PITCH + 64 * kt + 16 * g;  // k = 32kt+8g+j
    union { u32x4 u; bf16x8 s; } uv;
    uv.u = *(const u32x4*)rp;
    bfr[kt] = uv.s;
  }
}

__global__ __launch_bounds__(256, 2) void fused_mfma_kernel(
    const float* __restrict__ x, const uint8_t* __restrict__ wsb,
    float* __restrict__ out)
{
  // Entire ws image (weight fragments + params) staged once per block.
  __shared__ __align__(16) uint8_t wlds[WS_STAGE];
  __shared__ __align__(16) uint8_t bnc[4][16 * PITCH];  // per-wave bounce tiles

  const int t = threadIdx.x;
  const int w = t >> 6, l = t & 63, g = (l >> 4) & 3, c = l & 15;
  const size_t rowbase = (size_t)blockIdx.x * 64;

  // Stage ws -> LDS: 13 chunks of 4KB (256 lanes x 16B), linear both sides.
#pragma unroll
  for (int i = 0; i < 13; ++i) {
    const int off = i * 4096 + t * 16;
    if (off < WS_STAGE) {
      __builtin_amdgcn_global_load_lds(
          (const __attribute__((address_space(1))) void*)(wsb + off),
          (__attribute__((address_space(3))) void*)(wlds + off), 16, 0, 0);
    }
  }
  __syncthreads();   // drains vmcnt -> staged image visible block-wide

  const float* pars = (const float*)(wlds + PAR);
  const float inv1 = pars[400], inv2 = pars[401], inv3 = pars[402], So = pars[403];

  // this lane's batch row (B-fragment n = l&15); k-slice owned: 8g..8g+7 (+32s)
  const float* __restrict__ xrow = x + (rowbase + 16 * w + c) * IN_;

  f32x4 acc[4];
#pragma unroll
  for (int ht = 0; ht < 4; ++ht) acc[ht] = f32x4{0.f, 0.f, 0.f, 0.f};

  // ---- Layer 1: 8 k-tiles of 32, 3 exact bf16 limbs; A-frags via ds_read_b128 ----
#pragma unroll
  for (int s = 0; s < 8; ++s) {
    u32x4 wf[4];
#pragma unroll
    for (int ht = 0; ht < 4; ++ht)
      wf[ht] = *(const u32x4*)(wlds + W1F + (size_t)(((ht * 8 + s) * 64) + l) * 16);

    const f32x4 e0 = *(const f32x4*)(xrow + 32 * s + 8 * g);
    const f32x4 e1 = *(const f32x4*)(xrow + 32 * s + 8 * g + 4);
    const float el[8] = {e0.x, e0.y, e0.z, e0.w, e1.x, e1.y, e1.z, e1.w};

    float d[8], e2[8];
#pragma unroll
    for (int q = 0; q < 8; ++q) d[q] = el[q] - truncbf(el[q]);   // exact
#pragma unroll
    for (int q = 0; q < 8; ++q) e2[q] = d[q] - truncbf(d[q]);    // exact

    union { uint32_t u[4]; bf16x8 v; } bh, bl1, bl2;
#pragma unroll
    for (int q = 0; q < 4; ++q) {
      bh.u[q]  = packbf(el[2 * q], el[2 * q + 1]);
      bl1.u[q] = packbf(d[2 * q],  d[2 * q + 1]);
      bl2.u[q] = packbf(e2[2 * q], e2[2 * q + 1]);
    }
#pragma unroll
    for (int ht = 0; ht < 4; ++ht) acc[ht] = MFMA(wf[ht], bh.v,  acc[ht]);
#pragma unroll
    for (int ht = 0; ht < 4; ++ht) acc[ht] = MFMA(wf[ht], bl1.v, acc[ht]);
#pragma unroll
    for (int ht = 0; ht < 4; ++ht) acc[ht] = MFMA(wf[ht], bl2.v, acc[ht]);
  }

  uint8_t* bw = &bnc[w][0];
  bf16x8 bfr[2];

  // ---- Layer 2 ----
  epilog(acc, pars, 0, inv1, bw, g, c, bfr);
  f32x4 a2[4];
#pragma unroll
  for (int ht = 0; ht < 4; ++ht) a2[ht] = f32x4{0.f, 0.f, 0.f, 0.f};
#pragma unroll
  for (int kt = 0; kt < 2; ++kt) {
#pragma unroll
    for (int ht = 0; ht < 4; ++ht) {
      const u32x4 wf = *(const u32x4*)(wlds + W2F + (size_t)(((ht * 2 + kt) * 64) + l) * 16);
      a2[ht] = MFMA(wf, bfr[kt], a2[ht]);
    }
  }

  // ---- Layer 3 ----
  epilog(a2, pars, 1, inv2, bw, g, c, bfr);
  f32x4 a3[4];
#pragma unroll
  for (int ht = 0; ht < 4; ++ht) a3[ht] = f32x4{0.f, 0.f, 0.f, 0.f};
#pragma unroll
  for (int kt = 0; kt < 2; ++kt) {
#pragma unroll
    for (int ht = 0; ht < 4; ++ht) {
      const u32x4 wf = *(const u32x4*)(wlds + W3F + (size_t)(((ht * 2 + kt) * 64) + l) * 16);
      a3[ht] = MFMA(wf, bfr[kt], a3[ht]);
    }
  }

  // ---- Output layer ----
  epilog(a3, pars, 2, inv3, bw, g, c, bfr);
  f32x4 ao = f32x4{0.f, 0.f, 0.f, 0.f};
#pragma unroll
  for (int kt = 0; kt < 2; ++kt) {
    const u32x4 wf = *(const u32x4*)(wlds + WOF + (size_t)((kt * 64) + l) * 16);
    ao = MFMA(wf, bfr[kt], ao);
  }

  const float bo0 = pars[384 + 4 * g + 0];
  const float bo1 = pars[384 + 4 * g + 1];
  const float bo2 = pars[384 + 4 * g + 2];
  const float bo3 = pars[384 + 4 * g + 3];
  f32x4 o;
  o.x = fmaf(ao.x, So, bo0);
  o.y = fmaf(ao.y, So, bo1);
  o.z = fmaf(ao.z, So, bo2);
  o.w = fmaf(ao.w, So, bo3);
  if (g < 3)  // out channels 4g..4g+3; only 0..11 exist
    *(f32x4*)(out + (rowbase + 16 * w + c) * C_ + 4 * g) = o;
}

extern "C" void kernel_launch(void* const* d_in, const int* in_sizes, int n_in,
                              void* d_out, int out_size, void* d_ws, size_t ws_size,
                              hipStream_t stream) {
  // 0:x 1:W1 2:g1 3:b1 4:s1 5:W2 6:g2 7:b2 8:s2 9:W3 10:g3 11:b3 12:s3 13:Wo 14:bo
  const float* x  = (const float*)d_in[0];
  const float* W1 = (const float*)d_in[1];
  const float* g1 = (const float*)d_in[2];
  const float* b1 = (const float*)d_in[3];
  const float* s1 = (const float*)d_in[4];
  const float* W2 = (const float*)d_in[5];
  const float* g2 = (const float*)d_in[6];
  const float* b2 = (const float*)d_in[7];
  const float* s2 = (const float*)d_in[8];
  const float* W3 = (const float*)d_in[9];
  const float* g3 = (const float*)d_in[10];
  const float* b3 = (const float*)d_in[11];
  const float* s3 = (const float*)d_in[12];
  const float* Wo = (const float*)d_in[13];
  const float* bo = (const float*)d_in[14];

  uint8_t* ws = (uint8_t*)d_ws;
  float* out = (float*)d_out;

  prep_kernel<<<4, 1024, 0, stream>>>(W1, W2, W3, Wo, g1, b1, s1, g2, b2, s2,
                                      g3, b3, s3, bo, ws);
  fused_mfma_kernel<<<B_ / 64, 256, 0, stream>>>(x, ws, out);
}

// Round 11
// 41.605 us; speedup vs baseline: 1.6016x; 1.0991x over previous
//
#include <hip/hip_runtime.h>
#include <stdint.h>

// QuantDenseModelLarge on gfx950 — MFMA formulation.
// Round 11 = round 10 (45.7 µs) + occupancy: 512-thread blocks (8 waves, 128 rows),
// 4 waves/SIMD (2 blocks/CU x 8 waves), ws-staging traffic halved, first-2-k-tile
// x loads hoisted above the staging barrier (vmcnt(0) drain completes them free).
//
// Theory: round-10's 45.7 µs = non-overlapping pipe terms (x-stream 51K cy,
// VALU 20K, LDS 13K, staging 8K per CU) at only 2 waves/SIMD. Double the waves
// -> overlap -> approach the 22 µs x-stream floor.
//
// Exact identities:
//   quant weights = qw * sw, qw int in [-7,7]  -> exact in bf16
//   QuantReLU out = qa * s,  qa int in [0,255] -> exact in bf16
//   layers 2/3/out: D = sum(qa*qw) exact in f32; y = D*(s*sw)
//   layer 1: x == hi + lo1 + lo2 EXACTLY (3 bf16 truncation limbs cover 24 bits)
//
// MFMA layout (hardware-verified via learn_hip m89/m92 ref-checked GEMMs):
//   A (16x32): lane l holds A[m = l&15][k = 8*(l>>4) + j], j=0..7
//   B (32x16): lane l holds B[k = 8*(l>>4) + j][n = l&15]
//   C/D      : lane l, reg r holds D[row = 4*(l>>4) + r][col = l&15]

typedef __attribute__((ext_vector_type(4))) float  f32x4;
typedef __attribute__((ext_vector_type(8))) short  bf16x8;
typedef __attribute__((ext_vector_type(4))) unsigned int u32x4;

namespace {
constexpr int B_  = 131072;
constexpr int IN_ = 256;
constexpr int H_  = 58;
constexpr int C_  = 12;

// ws byte offsets (also the LDS image offsets after staging)
constexpr int W1F = 0;        // [ht4][kt8][lane64][j8] bf16 = 32768 B
constexpr int W2F = 32768;    // [ht4][kt2][lane64][j8] bf16 =  8192 B
constexpr int W3F = 40960;    //                                8192 B
constexpr int WOF = 49152;    // [kt2][lane64][j8]      bf16 =  2048 B
constexpr int PAR = 51200;    // 3*64 {A,b} f32 | bo[16] | {inv1,inv2,inv3,So}
constexpr int WS_STAGE = 52816;  // PAR + 404*4, multiple of 16
constexpr int PITCH = 144;    // bounce-tile row pitch (bytes): 128 data + 16 pad
}

__device__ __forceinline__ uint32_t fu(float f) { return __float_as_uint(f); }
__device__ __forceinline__ float    uf(uint32_t u) { return __uint_as_float(u); }
__device__ __forceinline__ float    truncbf(float v) { return uf(fu(v) & 0xffff0000u); }
// pack bf16(a) into low16, bf16(b) into high16 (truncation; exact for ints/limbs)
__device__ __forceinline__ uint32_t packbf(float a, float b) {
  return (fu(a) >> 16) | (fu(b) & 0xffff0000u);
}

__device__ __forceinline__ f32x4 MFMA(u32x4 a, bf16x8 b, f32x4 c) {
  union { u32x4 u; bf16x8 s; } ua; ua.u = a;
  return __builtin_amdgcn_mfma_f32_16x16x32_bf16(ua.s, b, c, 0, 0, 0);
}

// ---------------- prep: quantize + fragment-major arrange + param tables ----------------
__global__ void prep_kernel(
    const float* __restrict__ W1, const float* __restrict__ W2,
    const float* __restrict__ W3, const float* __restrict__ Wo,
    const float* __restrict__ g1, const float* __restrict__ b1, const float* __restrict__ s1,
    const float* __restrict__ g2, const float* __restrict__ b2, const float* __restrict__ s2,
    const float* __restrict__ g3, const float* __restrict__ b3, const float* __restrict__ s3,
    const float* __restrict__ bo,
    uint8_t* __restrict__ wsb)
{
  __shared__ float red[1024];
  const int t = threadIdx.x;
  const int blk = blockIdx.x;
  const float* W; int n;
  switch (blk) {
    case 0: W = W1; n = H_ * IN_; break;
    case 1: W = W2; n = H_ * H_;  break;
    case 2: W = W3; n = H_ * H_;  break;
    default: W = Wo; n = C_ * H_; break;
  }
  float m = 0.f;
  for (int i = t; i < n; i += 1024) m = fmaxf(m, fabsf(W[i]));
  red[t] = m;
  __syncthreads();
  for (int s = 512; s > 0; s >>= 1) { if (t < s) red[t] = fmaxf(red[t], red[t + s]); __syncthreads(); }
  const float sw = red[0] / 7.0f;   // per-tensor symmetric, qmax = 7

  float* pp = (float*)(wsb + PAR);

  if (blk == 0) {
    unsigned short* fr = (unsigned short*)(wsb + W1F);
    for (int i = t; i < 16384; i += 1024) {
      const int j = i & 7, ln = (i >> 3) & 63, kt = (i >> 9) & 7, ht = (i >> 12) & 3;
      const int h = (ht << 4) | (ln & 15);
      const int k = (kt << 5) | (((ln >> 4) & 3) << 3) | j;
      float q = 0.f;
      if (h < H_) q = fminf(fmaxf(rintf(W1[h * IN_ + k] / sw), -7.f), 7.f);
      fr[i] = (unsigned short)(fu(q) >> 16);   // small ints exact in bf16
    }
    if (t < 64) {
      pp[2 * t]     = (t < H_) ? sw * g1[t] : 0.f;
      pp[2 * t + 1] = (t < H_) ? b1[t] : 0.f;
    }
    if (t == 0) pp[400] = 1.0f / s1[0];
  } else if (blk == 1) {
    unsigned short* fr = (unsigned short*)(wsb + W2F);
    for (int i = t; i < 4096; i += 1024) {
      const int j = i & 7, ln = (i >> 3) & 63, kt = (i >> 9) & 1, ht = (i >> 10) & 3;
      const int h = (ht << 4) | (ln & 15);
      const int k = (kt << 5) | (((ln >> 4) & 3) << 3) | j;
      float q = 0.f;
      if (h < H_ && k < H_) q = fminf(fmaxf(rintf(W2[h * H_ + k] / sw), -7.f), 7.f);
      fr[i] = (unsigned short)(fu(q) >> 16);
    }
    if (t < 64) {
      pp[128 + 2 * t]     = (t < H_) ? s1[0] * sw * g2[t] : 0.f;
      pp[128 + 2 * t + 1] = (t < H_) ? b2[t] : 0.f;
    }
    if (t == 0) pp[401] = 1.0f / s2[0];
  } else if (blk == 2) {
    unsigned short* fr = (unsigned short*)(wsb + W3F);
    for (int i = t; i < 4096; i += 1024) {
      const int j = i & 7, ln = (i >> 3) & 63, kt = (i >> 9) & 1, ht = (i >> 10) & 3;
      const int h = (ht << 4) | (ln & 15);
      const int k = (kt << 5) | (((ln >> 4) & 3) << 3) | j;
      float q = 0.f;
      if (h < H_ && k < H_) q = fminf(fmaxf(rintf(W3[h * H_ + k] / sw), -7.f), 7.f);
      fr[i] = (unsigned short)(fu(q) >> 16);
    }
    if (t < 64) {
      pp[256 + 2 * t]     = (t < H_) ? s2[0] * sw * g3[t] : 0.f;
      pp[256 + 2 * t + 1] = (t < H_) ? b3[t] : 0.f;
    }
    if (t == 0) pp[402] = 1.0f / s3[0];
  } else {
    unsigned short* fr = (unsigned short*)(wsb + WOF);
    for (int i = t; i < 1024; i += 1024) {
      const int j = i & 7, ln = (i >> 3) & 63, kt = (i >> 9) & 1;
      const int h = ln & 15;
      const int k = (kt << 5) | (((ln >> 4) & 3) << 3) | j;
      float q = 0.f;
      if (h < C_ && k < H_) q = fminf(fmaxf(rintf(Wo[h * H_ + k] / sw), -7.f), 7.f);
      fr[i] = (unsigned short)(fu(q) >> 16);
    }
    if (t < 16) pp[384 + t] = (t < C_) ? bo[t] : 0.f;
    if (t == 0) pp[403] = s3[0] * sw;
  }
}

// ---------------- epilogue: BN + QuantReLU -> bf16 ints -> per-wave LDS bounce -> B-frags ----------------
__device__ __forceinline__ void epilog(
    const f32x4 (&acc)[4], const float* pars, int L, float inv,
    uint8_t* bw, int g, int c, bf16x8 (&bfr)[2])
{
  const float* pb = pars + L * 128 + 8 * g;   // {A(h),b(h)} pairs, h = 16ht+4g+r
#pragma unroll
  for (int ht = 0; ht < 4; ++ht) {
    float q[4];
#pragma unroll
    for (int r = 0; r < 4; ++r) {
      const float y = fmaf(acc[ht][r], pb[32 * ht + 2 * r], pb[32 * ht + 2 * r + 1]);
      q[r] = fminf(rintf(fmaxf(y, 0.f) * inv), 255.f);
    }
    uint8_t* bp = bw + c * PITCH + 32 * ht + 8 * g;   // row c, bytes 2h..2h+7
    *(uint32_t*)(bp)     = packbf(q[0], q[1]);
    *(uint32_t*)(bp + 4) = packbf(q[2], q[3]);
  }
  // same-wave cross-lane exchange: DS ops from one wave are processed in order
#pragma unroll
  for (int kt = 0; kt < 2; ++kt) {
    const uint8_t* rp = bw + c * PITCH + 64 * kt + 16 * g;  // k = 32kt+8g+j
    union { u32x4 u; bf16x8 s; } uv;
    uv.u = *(const u32x4*)rp;
    bfr[kt] = uv.s;
  }
}

__global__ __launch_bounds__(512, 4) void fused_mfma_kernel(
    const float* __restrict__ x, const uint8_t* __restrict__ wsb,
    float* __restrict__ out)
{
  // Entire ws image (weight fragments + params) staged once per block.
  __shared__ __align__(16) uint8_t wlds[WS_STAGE];
  __shared__ __align__(16) uint8_t bnc[8][16 * PITCH];  // per-wave bounce tiles

  const int t = threadIdx.x;
  const int w = t >> 6, l = t & 63, g = (l >> 4) & 3, c = l & 15;
  const size_t rowbase = (size_t)blockIdx.x * 128;

  // Stage ws -> LDS: 7 chunks of 8KB (512 lanes x 16B), linear both sides.
#pragma unroll
  for (int i = 0; i < 7; ++i) {
    const int off = i * 8192 + t * 16;
    if (off < WS_STAGE) {
      __builtin_amdgcn_global_load_lds(
          (const __attribute__((address_space(1))) void*)(wsb + off),
          (__attribute__((address_space(3))) void*)(wlds + off), 16, 0, 0);
    }
  }

  // this lane's batch row (B-fragment n = l&15); k-slice owned: 8g..8g+7 (+32s)
  const float* __restrict__ xrow = x + (rowbase + 16 * w + c) * IN_;

  // Hoist k-tiles 0/1 x loads above the barrier: the barrier's vmcnt(0) drain
  // completes them alongside the staging DMAs -> no post-barrier stall.
  f32x4 xpre[4];
  xpre[0] = *(const f32x4*)(xrow + 8 * g);
  xpre[1] = *(const f32x4*)(xrow + 8 * g + 4);
  xpre[2] = *(const f32x4*)(xrow + 32 + 8 * g);
  xpre[3] = *(const f32x4*)(xrow + 32 + 8 * g + 4);

  __syncthreads();   // drains vmcnt -> staged image + xpre ready

  const float* pars = (const float*)(wlds + PAR);
  const float inv1 = pars[400], inv2 = pars[401], inv3 = pars[402], So = pars[403];

  f32x4 acc[4];
#pragma unroll
  for (int ht = 0; ht < 4; ++ht) acc[ht] = f32x4{0.f, 0.f, 0.f, 0.f};

  // ---- Layer 1: 8 k-tiles of 32, 3 exact bf16 limbs; A-frags via ds_read_b128 ----
#pragma unroll
  for (int s = 0; s < 8; ++s) {
    u32x4 wf[4];
#pragma unroll
    for (int ht = 0; ht < 4; ++ht)
      wf[ht] = *(const u32x4*)(wlds + W1F + (size_t)(((ht * 8 + s) * 64) + l) * 16);

    const f32x4 e0 = (s == 0) ? xpre[0] : (s == 1) ? xpre[2]
                     : *(const f32x4*)(xrow + 32 * s + 8 * g);
    const f32x4 e1 = (s == 0) ? xpre[1] : (s == 1) ? xpre[3]
                     : *(const f32x4*)(xrow + 32 * s + 8 * g + 4);
    const float el[8] = {e0.x, e0.y, e0.z, e0.w, e1.x, e1.y, e1.z, e1.w};

    float d[8], e2[8];
#pragma unroll
    for (int q = 0; q < 8; ++q) d[q] = el[q] - truncbf(el[q]);   // exact
#pragma unroll
    for (int q = 0; q < 8; ++q) e2[q] = d[q] - truncbf(d[q]);    // exact

    union { uint32_t u[4]; bf16x8 v; } bh, bl1, bl2;
#pragma unroll
    for (int q = 0; q < 4; ++q) {
      bh.u[q]  = packbf(el[2 * q], el[2 * q + 1]);
      bl1.u[q] = packbf(d[2 * q],  d[2 * q + 1]);
      bl2.u[q] = packbf(e2[2 * q], e2[2 * q + 1]);
    }
#pragma unroll
    for (int ht = 0; ht < 4; ++ht) acc[ht] = MFMA(wf[ht], bh.v,  acc[ht]);
#pragma unroll
    for (int ht = 0; ht < 4; ++ht) acc[ht] = MFMA(wf[ht], bl1.v, acc[ht]);
#pragma unroll
    for (int ht = 0; ht < 4; ++ht) acc[ht] = MFMA(wf[ht], bl2.v, acc[ht]);
  }

  uint8_t* bw = &bnc[w][0];
  bf16x8 bfr[2];

  // ---- Layer 2 ----
  epilog(acc, pars, 0, inv1, bw, g, c, bfr);
  f32x4 a2[4];
#pragma unroll
  for (int ht = 0; ht < 4; ++ht) a2[ht] = f32x4{0.f, 0.f, 0.f, 0.f};
#pragma unroll
  for (int kt = 0; kt < 2; ++kt) {
#pragma unroll
    for (int ht = 0; ht < 4; ++ht) {
      const u32x4 wf = *(const u32x4*)(wlds + W2F + (size_t)(((ht * 2 + kt) * 64) + l) * 16);
      a2[ht] = MFMA(wf, bfr[kt], a2[ht]);
    }
  }

  // ---- Layer 3 ----
  epilog(a2, pars, 1, inv2, bw, g, c, bfr);
  f32x4 a3[4];
#pragma unroll
  for (int ht = 0; ht < 4; ++ht) a3[ht] = f32x4{0.f, 0.f, 0.f, 0.f};
#pragma unroll
  for (int kt = 0; kt < 2; ++kt) {
#pragma unroll
    for (int ht = 0; ht < 4; ++ht) {
      const u32x4 wf = *(const u32x4*)(wlds + W3F + (size_t)(((ht * 2 + kt) * 64) + l) * 16);
      a3[ht] = MFMA(wf, bfr[kt], a3[ht]);
    }
  }

  // ---- Output layer ----
  epilog(a3, pars, 2, inv3, bw, g, c, bfr);
  f32x4 ao = f32x4{0.f, 0.f, 0.f, 0.f};
#pragma unroll
  for (int kt = 0; kt < 2; ++kt) {
    const u32x4 wf = *(const u32x4*)(wlds + WOF + (size_t)((kt * 64) + l) * 16);
    ao = MFMA(wf, bfr[kt], ao);
  }

  const float bo0 = pars[384 + 4 * g + 0];
  const float bo1 = pars[384 + 4 * g + 1];
  const float bo2 = pars[384 + 4 * g + 2];
  const float bo3 = pars[384 + 4 * g + 3];
  f32x4 o;
  o.x = fmaf(ao.x, So, bo0);
  o.y = fmaf(ao.y, So, bo1);
  o.z = fmaf(ao.z, So, bo2);
  o.w = fmaf(ao.w, So, bo3);
  if (g < 3)  // out channels 4g..4g+3; only 0..11 exist
    *(f32x4*)(out + (rowbase + 16 * w + c) * C_ + 4 * g) = o;
}

extern "C" void kernel_launch(void* const* d_in, const int* in_sizes, int n_in,
                              void* d_out, int out_size, void* d_ws, size_t ws_size,
                              hipStream_t stream) {
  // 0:x 1:W1 2:g1 3:b1 4:s1 5:W2 6:g2 7:b2 8:s2 9:W3 10:g3 11:b3 12:s3 13:Wo 14:bo
  const float* x  = (const float*)d_in[0];
  const float* W1 = (const float*)d_in[1];
  const float* g1 = (const float*)d_in[2];
  const float* b1 = (const float*)d_in[3];
  const float* s1 = (const float*)d_in[4];
  const float* W2 = (const float*)d_in[5];
  const float* g2 = (const float*)d_in[6];
  const float* b2 = (const float*)d_in[7];
  const float* s2 = (const float*)d_in[8];
  const float* W3 = (const float*)d_in[9];
  const float* g3 = (const float*)d_in[10];
  const float* b3 = (const float*)d_in[11];
  const float* s3 = (const float*)d_in[12];
  const float* Wo = (const float*)d_in[13];
  const float* bo = (const float*)d_in[14];

  uint8_t* ws = (uint8_t*)d_ws;
  float* out = (float*)d_out;

  prep_kernel<<<4, 1024, 0, stream>>>(W1, W2, W3, Wo, g1, b1, s1, g2, b2, s2,
                                      g3, b3, s3, bo, ws);
  fused_mfma_kernel<<<B_ / 128, 512, 0, stream>>>(x, ws, out);
}

// Round 12
// 40.959 us; speedup vs baseline: 1.6268x; 1.0158x over previous
//
#include <hip/hip_runtime.h>
#include <stdint.h>

// QuantDenseModelLarge on gfx950 — MFMA formulation.
// Round 12 = round 11 (41.6 µs) + VALU diet:
//   - epilog: inv pre-folded into BN params at prep (A'=A/s, b'=b/s);
//     q = fmed3(rintf(fmaf(acc,A',b')), 0, 255)  -> 3 VALU/elem (was 5)
//   - packbf via v_perm_b32 builtin (1 instr, was up to 3)
// Theory: at 4 waves/SIMD the residual 100K cy/CU is VALU-throughput-dominated
// (limb split ~27K + epilogs ~15K + addr ~10K); cut instruction count.
//
// Exact identities:
//   quant weights = qw * sw, qw int in [-7,7]  -> exact in bf16
//   QuantReLU out = qa * s,  qa int in [0,255] -> exact in bf16
//   layers 2/3/out: D = sum(qa*qw) exact in f32; y = D*(s*sw)
//   layer 1: x == hi + lo1 + lo2 EXACTLY (3 bf16 truncation limbs cover 24 bits)
//   rint(max(y,0)) == med3(rint(y), 0, 255) for the clamp (rint monotone, rint(0)=0)
//
// MFMA layout (hardware-verified via learn_hip m89/m92 ref-checked GEMMs):
//   A (16x32): lane l holds A[m = l&15][k = 8*(l>>4) + j], j=0..7
//   B (32x16): lane l holds B[k = 8*(l>>4) + j][n = l&15]
//   C/D      : lane l, reg r holds D[row = 4*(l>>4) + r][col = l&15]

typedef __attribute__((ext_vector_type(4))) float  f32x4;
typedef __attribute__((ext_vector_type(8))) short  bf16x8;
typedef __attribute__((ext_vector_type(4))) unsigned int u32x4;

namespace {
constexpr int B_  = 131072;
constexpr int IN_ = 256;
constexpr int H_  = 58;
constexpr int C_  = 12;

// ws byte offsets (also the LDS image offsets after staging)
constexpr int W1F = 0;        // [ht4][kt8][lane64][j8] bf16 = 32768 B
constexpr int W2F = 32768;    // [ht4][kt2][lane64][j8] bf16 =  8192 B
constexpr int W3F = 40960;    //                                8192 B
constexpr int WOF = 49152;    // [kt2][lane64][j8]      bf16 =  2048 B
constexpr int PAR = 51200;    // 3*64 {A',b'} f32 | bo[16] | {unused x3, So}
constexpr int WS_STAGE = 52816;  // PAR + 404*4, multiple of 16
constexpr int PITCH = 144;    // bounce-tile row pitch (bytes): 128 data + 16 pad
}

__device__ __forceinline__ uint32_t fu(float f) { return __float_as_uint(f); }
__device__ __forceinline__ float    uf(uint32_t u) { return __uint_as_float(u); }
__device__ __forceinline__ float    truncbf(float v) { return uf(fu(v) & 0xffff0000u); }
// pack bf16(a) into low16, bf16(b) into high16 — single v_perm_b32.
// perm(src0,src1,sel): sel bytes 0-3 pick src1 bytes, 4-7 pick src0 bytes.
// 0x07060302: dst = { src1[31:16] (low), src0[31:16] (high) }.
__device__ __forceinline__ uint32_t packbf(float a, float b) {
  return __builtin_amdgcn_perm(fu(b), fu(a), 0x07060302u);
}

__device__ __forceinline__ f32x4 MFMA(u32x4 a, bf16x8 b, f32x4 c) {
  union { u32x4 u; bf16x8 s; } ua; ua.u = a;
  return __builtin_amdgcn_mfma_f32_16x16x32_bf16(ua.s, b, c, 0, 0, 0);
}

// ---------------- prep: quantize + fragment-major arrange + param tables ----------------
__global__ void prep_kernel(
    const float* __restrict__ W1, const float* __restrict__ W2,
    const float* __restrict__ W3, const float* __restrict__ Wo,
    const float* __restrict__ g1, const float* __restrict__ b1, const float* __restrict__ s1,
    const float* __restrict__ g2, const float* __restrict__ b2, const float* __restrict__ s2,
    const float* __restrict__ g3, const float* __restrict__ b3, const float* __restrict__ s3,
    const float* __restrict__ bo,
    uint8_t* __restrict__ wsb)
{
  __shared__ float red[1024];
  const int t = threadIdx.x;
  const int blk = blockIdx.x;
  const float* W; int n;
  switch (blk) {
    case 0: W = W1; n = H_ * IN_; break;
    case 1: W = W2; n = H_ * H_;  break;
    case 2: W = W3; n = H_ * H_;  break;
    default: W = Wo; n = C_ * H_; break;
  }
  float m = 0.f;
  for (int i = t; i < n; i += 1024) m = fmaxf(m, fabsf(W[i]));
  red[t] = m;
  __syncthreads();
  for (int s = 512; s > 0; s >>= 1) { if (t < s) red[t] = fmaxf(red[t], red[t + s]); __syncthreads(); }
  const float sw = red[0] / 7.0f;   // per-tensor symmetric, qmax = 7

  float* pp = (float*)(wsb + PAR);

  if (blk == 0) {
    unsigned short* fr = (unsigned short*)(wsb + W1F);
    for (int i = t; i < 16384; i += 1024) {
      const int j = i & 7, ln = (i >> 3) & 63, kt = (i >> 9) & 7, ht = (i >> 12) & 3;
      const int h = (ht << 4) | (ln & 15);
      const int k = (kt << 5) | (((ln >> 4) & 3) << 3) | j;
      float q = 0.f;
      if (h < H_) q = fminf(fmaxf(rintf(W1[h * IN_ + k] / sw), -7.f), 7.f);
      fr[i] = (unsigned short)(fu(q) >> 16);   // small ints exact in bf16
    }
    const float inv = 1.0f / s1[0];
    if (t < 64) {
      pp[2 * t]     = (t < H_) ? sw * g1[t] * inv : 0.f;   // A' = A/s1
      pp[2 * t + 1] = (t < H_) ? b1[t] * inv : 0.f;        // b' = b/s1
    }
  } else if (blk == 1) {
    unsigned short* fr = (unsigned short*)(wsb + W2F);
    for (int i = t; i < 4096; i += 1024) {
      const int j = i & 7, ln = (i >> 3) & 63, kt = (i >> 9) & 1, ht = (i >> 10) & 3;
      const int h = (ht << 4) | (ln & 15);
      const int k = (kt << 5) | (((ln >> 4) & 3) << 3) | j;
      float q = 0.f;
      if (h < H_ && k < H_) q = fminf(fmaxf(rintf(W2[h * H_ + k] / sw), -7.f), 7.f);
      fr[i] = (unsigned short)(fu(q) >> 16);
    }
    const float inv = 1.0f / s2[0];
    if (t < 64) {
      pp[128 + 2 * t]     = (t < H_) ? s1[0] * sw * g2[t] * inv : 0.f;
      pp[128 + 2 * t + 1] = (t < H_) ? b2[t] * inv : 0.f;
    }
  } else if (blk == 2) {
    unsigned short* fr = (unsigned short*)(wsb + W3F);
    for (int i = t; i < 4096; i += 1024) {
      const int j = i & 7, ln = (i >> 3) & 63, kt = (i >> 9) & 1, ht = (i >> 10) & 3;
      const int h = (ht << 4) | (ln & 15);
      const int k = (kt << 5) | (((ln >> 4) & 3) << 3) | j;
      float q = 0.f;
      if (h < H_ && k < H_) q = fminf(fmaxf(rintf(W3[h * H_ + k] / sw), -7.f), 7.f);
      fr[i] = (unsigned short)(fu(q) >> 16);
    }
    const float inv = 1.0f / s3[0];
    if (t < 64) {
      pp[256 + 2 * t]     = (t < H_) ? s2[0] * sw * g3[t] * inv : 0.f;
      pp[256 + 2 * t + 1] = (t < H_) ? b3[t] * inv : 0.f;
    }
  } else {
    unsigned short* fr = (unsigned short*)(wsb + WOF);
    for (int i = t; i < 1024; i += 1024) {
      const int j = i & 7, ln = (i >> 3) & 63, kt = (i >> 9) & 1;
      const int h = ln & 15;
      const int k = (kt << 5) | (((ln >> 4) & 3) << 3) | j;
      float q = 0.f;
      if (h < C_ && k < H_) q = fminf(fmaxf(rintf(Wo[h * H_ + k] / sw), -7.f), 7.f);
      fr[i] = (unsigned short)(fu(q) >> 16);
    }
    if (t < 16) pp[384 + t] = (t < C_) ? bo[t] : 0.f;
    if (t == 0) pp[403] = s3[0] * sw;   // So
  }
}

// ---------------- epilogue: BN+QuantReLU (prescaled) -> bf16 ints -> LDS bounce -> B-frags ----------------
__device__ __forceinline__ void epilog(
    const f32x4 (&acc)[4], const float* pars, int L,
    uint8_t* bw, int g, int c, bf16x8 (&bfr)[2])
{
  const float* pb = pars + L * 128 + 8 * g;   // {A'(h),b'(h)} pairs, h = 16ht+4g+r
#pragma unroll
  for (int ht = 0; ht < 4; ++ht) {
    float q[4];
#pragma unroll
    for (int r = 0; r < 4; ++r) {
      // q = clamp(rint(acc*A'+b'), 0, 255); relu folded into the clamp (rint monotone)
      q[r] = __builtin_amdgcn_fmed3f(
          rintf(fmaf(acc[ht][r], pb[32 * ht + 2 * r], pb[32 * ht + 2 * r + 1])),
          0.f, 255.f);
    }
    uint8_t* bp = bw + c * PITCH + 32 * ht + 8 * g;   // row c, bytes 2h..2h+7
    *(uint32_t*)(bp)     = packbf(q[0], q[1]);
    *(uint32_t*)(bp + 4) = packbf(q[2], q[3]);
  }
  // same-wave cross-lane exchange: DS ops from one wave are processed in order
#pragma unroll
  for (int kt = 0; kt < 2; ++kt) {
    const uint8_t* rp = bw + c * PITCH + 64 * kt + 16 * g;  // k = 32kt+8g+j
    union { u32x4 u; bf16x8 s; } uv;
    uv.u = *(const u32x4*)rp;
    bfr[kt] = uv.s;
  }
}

__global__ __launch_bounds__(512, 4) void fused_mfma_kernel(
    const float* __restrict__ x, const uint8_t* __restrict__ wsb,
    float* __restrict__ out)
{
  // Entire ws image (weight fragments + params) staged once per block.
  __shared__ __align__(16) uint8_t wlds[WS_STAGE];
  __shared__ __align__(16) uint8_t bnc[8][16 * PITCH];  // per-wave bounce tiles

  const int t = threadIdx.x;
  const int w = t >> 6, l = t & 63, g = (l >> 4) & 3, c = l & 15;
  const size_t rowbase = (size_t)blockIdx.x * 128;

  // Stage ws -> LDS: 7 chunks of 8KB (512 lanes x 16B), linear both sides.
#pragma unroll
  for (int i = 0; i < 7; ++i) {
    const int off = i * 8192 + t * 16;
    if (off < WS_STAGE) {
      __builtin_amdgcn_global_load_lds(
          (const __attribute__((address_space(1))) void*)(wsb + off),
          (__attribute__((address_space(3))) void*)(wlds + off), 16, 0, 0);
    }
  }

  // this lane's batch row (B-fragment n = l&15); k-slice owned: 8g..8g+7 (+32s)
  const float* __restrict__ xrow = x + (rowbase + 16 * w + c) * IN_;

  // Hoist k-tiles 0/1 x loads above the barrier: the barrier's vmcnt(0) drain
  // completes them alongside the staging DMAs -> no post-barrier stall.
  f32x4 xpre[4];
  xpre[0] = *(const f32x4*)(xrow + 8 * g);
  xpre[1] = *(const f32x4*)(xrow + 8 * g + 4);
  xpre[2] = *(const f32x4*)(xrow + 32 + 8 * g);
  xpre[3] = *(const f32x4*)(xrow + 32 + 8 * g + 4);

  __syncthreads();   // drains vmcnt -> staged image + xpre ready

  const float* pars = (const float*)(wlds + PAR);
  const float So = pars[403];

  f32x4 acc[4];
#pragma unroll
  for (int ht = 0; ht < 4; ++ht) acc[ht] = f32x4{0.f, 0.f, 0.f, 0.f};

  // ---- Layer 1: 8 k-tiles of 32, 3 exact bf16 limbs; A-frags via ds_read_b128 ----
#pragma unroll
  for (int s = 0; s < 8; ++s) {
    u32x4 wf[4];
#pragma unroll
    for (int ht = 0; ht < 4; ++ht)
      wf[ht] = *(const u32x4*)(wlds + W1F + (size_t)(((ht * 8 + s) * 64) + l) * 16);

    const f32x4 e0 = (s == 0) ? xpre[0] : (s == 1) ? xpre[2]
                     : *(const f32x4*)(xrow + 32 * s + 8 * g);
    const f32x4 e1 = (s == 0) ? xpre[1] : (s == 1) ? xpre[3]
                     : *(const f32x4*)(xrow + 32 * s + 8 * g + 4);
    const float el[8] = {e0.x, e0.y, e0.z, e0.w, e1.x, e1.y, e1.z, e1.w};

    float d[8], e2[8];
#pragma unroll
    for (int q = 0; q < 8; ++q) d[q] = el[q] - truncbf(el[q]);   // exact
#pragma unroll
    for (int q = 0; q < 8; ++q) e2[q] = d[q] - truncbf(d[q]);    // exact

    union { uint32_t u[4]; bf16x8 v; } bh, bl1, bl2;
#pragma unroll
    for (int q = 0; q < 4; ++q) {
      bh.u[q]  = packbf(el[2 * q], el[2 * q + 1]);
      bl1.u[q] = packbf(d[2 * q],  d[2 * q + 1]);
      bl2.u[q] = packbf(e2[2 * q], e2[2 * q + 1]);
    }
#pragma unroll
    for (int ht = 0; ht < 4; ++ht) acc[ht] = MFMA(wf[ht], bh.v,  acc[ht]);
#pragma unroll
    for (int ht = 0; ht < 4; ++ht) acc[ht] = MFMA(wf[ht], bl1.v, acc[ht]);
#pragma unroll
    for (int ht = 0; ht < 4; ++ht) acc[ht] = MFMA(wf[ht], bl2.v, acc[ht]);
  }

  uint8_t* bw = &bnc[w][0];
  bf16x8 bfr[2];

  // ---- Layer 2 ----
  epilog(acc, pars, 0, bw, g, c, bfr);
  f32x4 a2[4];
#pragma unroll
  for (int ht = 0; ht < 4; ++ht) a2[ht] = f32x4{0.f, 0.f, 0.f, 0.f};
#pragma unroll
  for (int kt = 0; kt < 2; ++kt) {
#pragma unroll
    for (int ht = 0; ht < 4; ++ht) {
      const u32x4 wf = *(const u32x4*)(wlds + W2F + (size_t)(((ht * 2 + kt) * 64) + l) * 16);
      a2[ht] = MFMA(wf, bfr[kt], a2[ht]);
    }
  }

  // ---- Layer 3 ----
  epilog(a2, pars, 1, bw, g, c, bfr);
  f32x4 a3[4];
#pragma unroll
  for (int ht = 0; ht < 4; ++ht) a3[ht] = f32x4{0.f, 0.f, 0.f, 0.f};
#pragma unroll
  for (int kt = 0; kt < 2; ++kt) {
#pragma unroll
    for (int ht = 0; ht < 4; ++ht) {
      const u32x4 wf = *(const u32x4*)(wlds + W3F + (size_t)(((ht * 2 + kt) * 64) + l) * 16);
      a3[ht] = MFMA(wf, bfr[kt], a3[ht]);
    }
  }

  // ---- Output layer ----
  epilog(a3, pars, 2, bw, g, c, bfr);
  f32x4 ao = f32x4{0.f, 0.f, 0.f, 0.f};
#pragma unroll
  for (int kt = 0; kt < 2; ++kt) {
    const u32x4 wf = *(const u32x4*)(wlds + WOF + (size_t)((kt * 64) + l) * 16);
    ao = MFMA(wf, bfr[kt], ao);
  }

  const float bo0 = pars[384 + 4 * g + 0];
  const float bo1 = pars[384 + 4 * g + 1];
  const float bo2 = pars[384 + 4 * g + 2];
  const float bo3 = pars[384 + 4 * g + 3];
  f32x4 o;
  o.x = fmaf(ao.x, So, bo0);
  o.y = fmaf(ao.y, So, bo1);
  o.z = fmaf(ao.z, So, bo2);
  o.w = fmaf(ao.w, So, bo3);
  if (g < 3)  // out channels 4g..4g+3; only 0..11 exist
    *(f32x4*)(out + (rowbase + 16 * w + c) * C_ + 4 * g) = o;
}

extern "C" void kernel_launch(void* const* d_in, const int* in_sizes, int n_in,
                              void* d_out, int out_size, void* d_ws, size_t ws_size,
                              hipStream_t stream) {
  // 0:x 1:W1 2:g1 3:b1 4:s1 5:W2 6:g2 7:b2 8:s2 9:W3 10:g3 11:b3 12:s3 13:Wo 14:bo
  const float* x  = (const float*)d_in[0];
  const float* W1 = (const float*)d_in[1];
  const float* g1 = (const float*)d_in[2];
  const float* b1 = (const float*)d_in[3];
  const float* s1 = (const float*)d_in[4];
  const float* W2 = (const float*)d_in[5];
  const float* g2 = (const float*)d_in[6];
  const float* b2 = (const float*)d_in[7];
  const float* s2 = (const float*)d_in[8];
  const float* W3 = (const float*)d_in[9];
  const float* g3 = (const float*)d_in[10];
  const float* b3 = (const float*)d_in[11];
  const float* s3 = (const float*)d_in[12];
  const float* Wo = (const float*)d_in[13];
  const float* bo = (const float*)d_in[14];

  uint8_t* ws = (uint8_t*)d_ws;
  float* out = (float*)d_out;

  prep_kernel<<<4, 1024, 0, stream>>>(W1, W2, W3, Wo, g1, b1, s1, g2, b2, s2,
                                      g3, b3, s3, bo, ws);
  fused_mfma_kernel<<<B_ / 128, 512, 0, stream>>>(x, ws, out);
}